// Round 20
// baseline (337.292 us; speedup 1.0000x reference)
//
#include <hip/hip_runtime.h>
#include <hip/hip_bf16.h>

#define DEVB 64
#define LSEQ 512
#define DDIM 600
#define KPAD 608   // Hhi row stride (fp16): 600 + zeroed tail, 16B-aligned rows

typedef short short8 __attribute__((ext_vector_type(8)));
typedef float f32x4 __attribute__((ext_vector_type(4)));
typedef _Float16 f16x8 __attribute__((ext_vector_type(8)));
typedef _Float16 f16x4 __attribute__((ext_vector_type(4)));

constexpr int LDP = 40;   // padded stride for fallback-wsum tiles (16B-aligned rows)

__device__ __forceinline__ unsigned short f2bf(float x) {
    union { float f; unsigned u; } v; v.f = x;
    unsigned r = v.u + 0x7fffu + ((v.u >> 16) & 1u);   // RNE
    return (unsigned short)(r >> 16);
}
__device__ __forceinline__ unsigned pk16(float a, float b) {
    union { _Float16 h[2]; unsigned u; } p;
    p.h[0] = (_Float16)a; p.h[1] = (_Float16)b;
    return p.u;
}
__device__ __forceinline__ f32x4 mfma16(short8 a, short8 b, f32x4 c) {
    return __builtin_amdgcn_mfma_f32_16x16x32_bf16(a, b, c, 0, 0, 0);
}
__device__ __forceinline__ f32x4 mfma16h(f16x8 a, f16x8 b, f32x4 c) {
    return __builtin_amdgcn_mfma_f32_16x16x32_f16(a, b, c, 0, 0, 0);
}

// global -> LDS direct DMA, 16 B per lane. LDS base must be wave-uniform;
// lane L lands at ldsbase + L*16.
typedef const __attribute__((address_space(1))) unsigned int* as1_u32p;
typedef __attribute__((address_space(3))) unsigned int* as3_u32p;
__device__ __forceinline__ void gll16(const void* g, void* l) {
    __builtin_amdgcn_global_load_lds((as1_u32p)g, (as3_u32p)l, 16, 0, 0);
}

// ---------------------------------------------------------------------------
// K0: transcvt3 — XT[b][d][r] = fp16(X[b][r][d]) for X in {P, H}, one grid of
//     EXACTLY DEVB*80 blocks (R19 crash: launched DEVB*160 -> b up to 191,
//     massive OOB). 64r x 128d strip per block; u32-paired LDS writes.
//     H half ALSO emits Hhi row-major [b][512][KPAD] fp16 (tail zeroed) so
//     attn_gemm can DMA its B operand. NOTE (R17): do NOT fuse with attn_gemm.
// ---------------------------------------------------------------------------
__global__ __launch_bounds__(256) void transcvt3(
    const float* __restrict__ P, const float* __restrict__ H,
    _Float16* __restrict__ pT, _Float16* __restrict__ hT,
    _Float16* __restrict__ Hhi)
{
    int blk = blockIdx.x;
    const float* X; _Float16* XT; _Float16* RM;
    const int half = DEVB * 40;
    if (blk < half) { X = P; XT = pT; RM = nullptr; }
    else { blk -= half; X = H; XT = hT; RM = Hhi; }

    int b   = blk / 40;
    int rem = blk % 40;
    int r0  = (rem / 5) << 6;       // 8 r-tiles of 64
    int d0  = (rem % 5) << 7;       // 5 d-strips of 128
    const float* Xb = X + (size_t)b * LSEQ * DDIM;

    __shared__ unsigned T32[2][64 * 33];
    const int t  = threadIdx.x;
    const int rp = t >> 3;          // 0..31 row-pair
    const int dc = (t & 7) << 3;    // 0..56

#pragma unroll
    for (int ht_ = 0; ht_ < 2; ++ht_) {
        int dd = d0 + (ht_ << 6) + dc;
        if (dd < DDIM) {            // 8-chunks fully valid or invalid (600%8==0)
            const float* s0 = Xb + (size_t)(r0 + 2 * rp) * DDIM + dd;
            const float* s1 = s0 + DDIM;
            float4 a0 = *(const float4*)s0, a1 = *(const float4*)(s0 + 4);
            float4 b0 = *(const float4*)s1, b1 = *(const float4*)(s1 + 4);
            float xa[8] = {a0.x, a0.y, a0.z, a0.w, a1.x, a1.y, a1.z, a1.w};
            float xb[8] = {b0.x, b0.y, b0.z, b0.w, b1.x, b1.y, b1.z, b1.w};
#pragma unroll
            for (int j = 0; j < 8; ++j)
                T32[ht_][(dc + j) * 33 + rp] = pk16(xa[j], xb[j]);
            if (RM) {
                f16x8 ha, hb;
#pragma unroll
                for (int j = 0; j < 8; ++j) {
                    ha[j] = (_Float16)xa[j];
                    hb[j] = (_Float16)xb[j];
                }
                _Float16* rm0 = RM + ((size_t)b * LSEQ + r0 + 2 * rp) * KPAD + dd;
                *(f16x8*)rm0          = ha;
                *(f16x8*)(rm0 + KPAD) = hb;
            }
        }
    }
    // zero the 600..607 tail of Hhi (once per row, from the d0==512 strip)
    if (RM && d0 == 512 && t < 64) {
        const f16x8 z = {0, 0, 0, 0, 0, 0, 0, 0};
        *(f16x8*)(RM + ((size_t)b * LSEQ + r0 + t) * KPAD + DDIM) = z;
    }
    __syncthreads();

    if (XT) {
        const int dl = t >> 2;          // 0..63
        const int q  = t & 3;
#pragma unroll
        for (int ht_ = 0; ht_ < 2; ++ht_) {
            int d = d0 + (ht_ << 6) + dl;
            if (d < DDIM) {
                unsigned buf[8];
#pragma unroll
                for (int i = 0; i < 8; ++i)
                    buf[i] = T32[ht_][dl * 33 + q * 8 + i];
                unsigned* dst = (unsigned*)(XT + ((size_t)b * DDIM + d) * LSEQ + r0) + q * 8;
                *(uint4*)(dst)     = *(uint4*)&buf[0];
                *(uint4*)(dst + 4) = *(uint4*)&buf[4];
            }
        }
    }
}

// ---------------------------------------------------------------------------
// K1: attn[b][p][h] = sum_d P[b][p][d] * H[b][h][d]   (fp32 out)
// A (P) read fp32 + hi/lo fp16 split in LDS-write phase (R9/R12 proven).
// B (H) DMA'd from prepacked Hhi fp16 via global_load_lds width=16 with
// pre-swizzled source (chunk XOR (row>>1)&3) — gemm_gll pattern, R16 proven.
// 48 KB dbuf, 0 conflicts. No 2nd launch_bounds arg (R10: VGPR spill).
// ---------------------------------------------------------------------------
__global__ __launch_bounds__(256) void attn_gemm(
    const float* __restrict__ P, const _Float16* __restrict__ Hhi,
    float* __restrict__ attn)
{
    const int bid = blockIdx.x;
    const int swz = (bid & 7) * 128 + (bid >> 3);   // 1024 blocks, 8 XCDs
    const int b  = swz >> 4;
    const int pt = ((swz >> 2) & 3) << 7;
    const int ht = (swz & 3) << 7;
    const float*    Pb = P   + ((size_t)b * LSEQ + pt) * DDIM;
    const _Float16* Hb = Hhi + ((size_t)b * LSEQ + ht) * KPAD;
    float* Ab = attn + (size_t)b * LSEQ * LSEQ;

    __shared__ _Float16 Ah[2][128 * 32], Al[2][128 * 32], Bh[2][128 * 32];

    const int t    = threadIdx.x;
    const int lane = t & 63;
    const int wave = t >> 6;
    const int wm = (wave >> 1) << 6;
    const int wn = (wave & 1) << 6;
    const int fr = lane & 15;
    const int fq = lane >> 4;
    const int srow = t >> 2;          // 0..63 (r=1 adds 64)
    const int sc8  = (t & 3) << 3;    // logical col chunk base (8 elems)

    const int wchunk = (t & 3) ^ ((srow >> 1) & 3);
    const int woff   = srow * 32 + (wchunk << 3);          // + r*64*32
    const int rcoff  = ((fq ^ ((fr >> 1) & 3)) << 3);

    // B staging via gll: wave covers rows 32w..32w+31, two 1KB calls.
    const int rowc0 = (wave << 5) + (lane >> 2);           // + 16*c
    auto bstage = [&](int buf, int k0) {
#pragma unroll
        for (int c = 0; c < 2; ++c) {
            int row = rowc0 + (c << 4);
            int lg  = (((lane & 3) ^ ((row >> 1) & 3)) << 3);
            int ldsoff = ((wave << 5) + (c << 4)) * 32;    // wave-uniform
            gll16(Hb + (size_t)row * KPAD + k0 + lg, &Bh[buf][ldsoff]);
        }
    };

    float4 pf[4];
    const float4 fz = {0.f, 0.f, 0.f, 0.f};
    auto issue = [&](int k0) {
        bool ok = (k0 + sc8) < DDIM;   // zero the 600..607 tail chunk
#pragma unroll
        for (int r = 0; r < 2; ++r) {
            size_t base = (size_t)(srow + (r << 6)) * DDIM + k0 + sc8;
            if (ok) {
                pf[r * 2 + 0] = *(const float4*)(Pb + base);
                pf[r * 2 + 1] = *(const float4*)(Pb + base + 4);
            } else {
                pf[r * 2 + 0] = fz; pf[r * 2 + 1] = fz;
            }
        }
    };
    auto wr = [&](int buf) {
#pragma unroll
        for (int r = 0; r < 2; ++r) {
            float4 a0 = pf[r * 2 + 0], a1 = pf[r * 2 + 1];
            float af[8] = {a0.x, a0.y, a0.z, a0.w, a1.x, a1.y, a1.z, a1.w};
            f16x8 hi, lo;
#pragma unroll
            for (int j = 0; j < 8; ++j) {
                hi[j] = (_Float16)af[j];
                lo[j] = (_Float16)(af[j] - (float)hi[j]);
            }
            int off = woff + (r << 11);                    // r*64*32
            *(f16x8*)&Ah[buf][off] = hi;
            *(f16x8*)&Al[buf][off] = lo;
        }
    };

    bstage(0, 0);
    issue(0);
    wr(0);
    issue(32);
    __syncthreads();

    f32x4 acc[4][4];
#pragma unroll
    for (int i = 0; i < 4; ++i)
#pragma unroll
        for (int j = 0; j < 4; ++j) acc[i][j] = (f32x4){0.f, 0.f, 0.f, 0.f};

    constexpr int NK = 19;   // ceil(600/32)
    int cur = 0;
    for (int it = 0; it < NK; ++it) {
        f16x8 ah[4], al[4], bh[4];
#pragma unroll
        for (int i = 0; i < 4; ++i) {
            int ra = (wm + (i << 4) + fr) * 32 + rcoff;
            int rb = (wn + (i << 4) + fr) * 32 + rcoff;
            ah[i] = *(const f16x8*)&Ah[cur][ra];
            al[i] = *(const f16x8*)&Al[cur][ra];
            bh[i] = *(const f16x8*)&Bh[cur][rb];
        }
        if (it + 1 < NK) {
            wr(cur ^ 1);                          // cvt + stage A tile it+1
            bstage(cur ^ 1, (it + 1) << 5);       // DMA B tile it+1
            if (it + 2 < NK) issue((it + 2) << 5);
        }
#pragma unroll
        for (int mi = 0; mi < 4; ++mi)
#pragma unroll
            for (int ni = 0; ni < 4; ++ni) {
                f32x4 c = acc[mi][ni];
                c = mfma16h(ah[mi], bh[ni], c);
                c = mfma16h(al[mi], bh[ni], c);
                acc[mi][ni] = c;
            }
        __syncthreads();
        cur ^= 1;
    }

#pragma unroll
    for (int mi = 0; mi < 4; ++mi)
#pragma unroll
        for (int ni = 0; ni < 4; ++ni)
#pragma unroll
            for (int j = 0; j < 4; ++j) {
                int p = pt + wm + (mi << 4) + (fq << 2) + j;
                int h = ht + wn + (ni << 4) + fr;
                Ab[(size_t)p * LSEQ + h] = acc[mi][ni][j];
            }
}

// ---------------------------------------------------------------------------
// K2: stats_w1 — ONE pass over attn per 32-row stripe (16 stripes/batch,
// grid DEVB*16 = 1024 blocks -> 4 blocks/CU; proven R18):
//   per-row (over h): W1 fp16 (hm-masked softmax); M1/R1 written only in
//   fallback mode (W1 == nullptr)
//   per-col partials (over p, pm-masked online): Mp/Tp/Sp [b][16][512]
// ---------------------------------------------------------------------------
__global__ __launch_bounds__(256) void stats_w1(
    const float* __restrict__ attn, const float* __restrict__ hmask,
    const float* __restrict__ pmask,
    float* __restrict__ M1, float* __restrict__ R1,
    _Float16* __restrict__ W1,
    float* __restrict__ Mp, float* __restrict__ Tp, float* __restrict__ Sp)
{
    int b      = blockIdx.x >> 4;
    int stripe = blockIdx.x & 15;
    int lane   = threadIdx.x & 63;
    int wave   = threadIdx.x >> 6;
    const float* hm = hmask + (b << 9);
    const float* pm = pmask + (b << 9);

    float4 m0 = *(const float4*)(hm + (lane << 3));
    float4 m1 = *(const float4*)(hm + (lane << 3) + 4);
    float mk[8] = {m0.x, m0.y, m0.z, m0.w, m1.x, m1.y, m1.z, m1.w};

    float cM[8], cT[8], cS[8];
#pragma unroll
    for (int j = 0; j < 8; ++j) { cM[j] = -1e30f; cT[j] = 0.f; cS[j] = 0.f; }

    for (int i = 0; i < 8; ++i) {
        int row   = (stripe << 5) + (wave << 3) + i;
        int rowid = (b << 9) + row;
        const float* rp = attn + (size_t)rowid * LSEQ + (lane << 3);
        float4 s0 = *(const float4*)rp;
        float4 s1 = *(const float4*)(rp + 4);
        float s[8] = {s0.x, s0.y, s0.z, s0.w, s1.x, s1.y, s1.z, s1.w};

        float v[8];
#pragma unroll
        for (int j = 0; j < 8; ++j) v[j] = s[j] * mk[j];
        float mx = -1e30f;
#pragma unroll
        for (int j = 0; j < 8; ++j) mx = fmaxf(mx, v[j]);
#pragma unroll
        for (int off = 32; off; off >>= 1) mx = fmaxf(mx, __shfl_xor(mx, off));

        float e[8], T = 0.f, S = 0.f;
#pragma unroll
        for (int j = 0; j < 8; ++j) { e[j] = __expf(v[j] - mx); T += mk[j] * e[j]; S += e[j]; }
#pragma unroll
        for (int off = 32; off; off >>= 1) { T += __shfl_xor(T, off); S += __shfl_xor(S, off); }
        float R = 1.f / (T + 1e-13f * S);

        if (W1) {
            union { f16x8 v8; _Float16 h[8]; } wv;
#pragma unroll
            for (int j = 0; j < 8; ++j) wv.h[j] = (_Float16)(mk[j] * e[j] * R);
            *(f16x8*)(W1 + (size_t)rowid * LSEQ + (lane << 3)) = wv.v8;
        } else if (lane == 0) {
            M1[rowid] = mx; R1[rowid] = R;
        }

        float pmv = pm[row];
#pragma unroll
        for (int j = 0; j < 8; ++j) {
            float v2 = s[j] * pmv;
            float nm = fmaxf(cM[j], v2);
            float sc = __expf(cM[j] - nm);
            float e2 = __expf(v2 - nm);
            cT[j] = cT[j] * sc + pmv * e2;
            cS[j] = cS[j] * sc + e2;
            cM[j] = nm;
        }
    }

    __shared__ float LM[4][512], LT[4][512], LS[4][512];
#pragma unroll
    for (int j = 0; j < 8; ++j) {
        int c = (lane << 3) + j;
        LM[wave][c] = cM[j]; LT[wave][c] = cT[j]; LS[wave][c] = cS[j];
    }
    __syncthreads();

    size_t base = (size_t)((b << 4) + stripe) * 512;
    for (int cc = threadIdx.x; cc < 512; cc += 256) {
        float gm = fmaxf(fmaxf(LM[0][cc], LM[1][cc]), fmaxf(LM[2][cc], LM[3][cc]));
        float gT = 0.f, gS = 0.f;
#pragma unroll
        for (int w = 0; w < 4; ++w) {
            float sc = __expf(LM[w][cc] - gm);
            gT += LT[w][cc] * sc;
            gS += LS[w][cc] * sc;
        }
        Mp[base + cc] = gm; Tp[base + cc] = gT; Sp[base + cc] = gS;
    }
}

// ---------------------------------------------------------------------------
// K3 (fallback only): col_merge — merge 16 stripe partials -> M2, R2
// ---------------------------------------------------------------------------
__global__ __launch_bounds__(256) void col_merge(
    const float* __restrict__ Mp, const float* __restrict__ Tp,
    const float* __restrict__ Sp, float* __restrict__ M2, float* __restrict__ R2)
{
    int b = blockIdx.x >> 1;
    int c = ((blockIdx.x & 1) << 8) + threadIdx.x;
    float gm = -1e30f, gT = 0.f, gS = 0.f;
#pragma unroll
    for (int st = 0; st < 16; ++st) {
        size_t idx = (size_t)((b << 4) + st) * 512 + c;
        float m = Mp[idx], tt = Tp[idx], ss = Sp[idx];
        float nm  = fmaxf(gm, m);
        float sc1 = __expf(gm - nm), sc2 = __expf(m - nm);
        gT = gT * sc1 + tt * sc2;
        gS = gS * sc1 + ss * sc2;
        gm = nm;
    }
    M2[(b << 9) + c] = gm;
    R2[(b << 9) + c] = 1.f / (gT + 1e-13f * gS);
}

// ---------------------------------------------------------------------------
// K4: w2gen3 — per-block 16-stripe merge then W2[b][h][p] fp16 via u32-paired
//     LDS transpose (proven R12). Tile = 64p x 128h.
// ---------------------------------------------------------------------------
__global__ __launch_bounds__(256) void w2gen3(
    const float* __restrict__ attn, const float* __restrict__ pmask,
    const float* __restrict__ Mp, const float* __restrict__ Tp,
    const float* __restrict__ Sp, _Float16* __restrict__ W2)
{
    int blk = blockIdx.x;
    int b  = blk >> 5;
    int p0 = ((blk >> 2) & 7) << 6;
    int h0 = (blk & 3) << 7;
    const float* Ab = attn + (size_t)b * LSEQ * LSEQ;
    const float* pm = pmask + (b << 9);

    __shared__ float sM[128], sR[128];
    __shared__ unsigned T32[128 * 33];
    const int t = threadIdx.x;
    if (t < 128) {
        float gm = -1e30f, gT = 0.f, gS = 0.f;
#pragma unroll
        for (int st = 0; st < 16; ++st) {
            size_t idx = (size_t)((b << 4) + st) * 512 + h0 + t;
            float m = Mp[idx], tt = Tp[idx], ss = Sp[idx];
            float nm  = fmaxf(gm, m);
            float sc1 = __expf(gm - nm), sc2 = __expf(m - nm);
            gT = gT * sc1 + tt * sc2;
            gS = gS * sc1 + ss * sc2;
            gm = nm;
        }
        sM[t] = gm;
        sR[t] = 1.f / (gT + 1e-13f * gS);
    }
    __syncthreads();

#pragma unroll
    for (int it = 0; it < 4; ++it) {
        int g  = t + (it << 8);
        int pp = g >> 5;           // 0..31 p-pair
        int hc = (g & 31) << 2;    // 0..124
        const float* s0 = Ab + (size_t)(p0 + 2 * pp) * LSEQ + h0 + hc;
        float4 xa = *(const float4*)s0;
        float4 xb = *(const float4*)(s0 + LSEQ);
        float pa = pm[p0 + 2 * pp];
        float pb = pm[p0 + 2 * pp + 1];
        float a[4] = {xa.x, xa.y, xa.z, xa.w};
        float bb[4] = {xb.x, xb.y, xb.z, xb.w};
#pragma unroll
        for (int j = 0; j < 4; ++j) {
            float wa = (pa != 0.f) ? __expf(a[j]  - sM[hc + j]) * sR[hc + j] : 0.f;
            float wb = (pb != 0.f) ? __expf(bb[j] - sM[hc + j]) * sR[hc + j] : 0.f;
            T32[(hc + j) * 33 + pp] = pk16(wa, wb);
        }
    }
    __syncthreads();

    const int hl = t >> 1;          // 0..127
    const int q  = t & 1;
    unsigned buf[16];
#pragma unroll
    for (int i = 0; i < 16; ++i)
        buf[i] = T32[hl * 33 + q * 16 + i];
    unsigned* dst = (unsigned*)(W2 + ((size_t)(b << 9) + h0 + hl) * LSEQ + p0) + q * 16;
#pragma unroll
    for (int i = 0; i < 4; ++i)
        *(uint4*)(dst + 4 * i) = *(uint4*)&buf[4 * i];
}

// ---------------------------------------------------------------------------
// K5: gemm_gll — out[b][m][d] = mask_m[m] * sum_k W[b][m][k] * BT[b][d][k]
//     m97-style: BK=32, dbuf, both operands via global_load_lds width=16,
//     pre-swizzled source (chunk XOR (row>>1)&3). 32 KB LDS. (proven R16)
// ---------------------------------------------------------------------------
__global__ __launch_bounds__(256) void gemm_gll(
    const _Float16* __restrict__ W, const _Float16* __restrict__ BT,
    const float* __restrict__ mask_m, float* __restrict__ out)
{
    const int bid = blockIdx.x;
    const int swz = (bid & 7) * 160 + (bid >> 3);   // 1280 blocks, 8 XCDs
    const int b   = swz / 20;
    const int rem = swz % 20;
    const int m0  = (rem / 5) << 7;
    const int n0  = (rem % 5) << 7;
    const _Float16* Wb = W  + (size_t)b * LSEQ * LSEQ;
    const _Float16* Bb = BT + (size_t)b * DDIM * LSEQ;

    __shared__ _Float16 Wl[2][128 * 32];
    __shared__ _Float16 Bl[2][128 * 32];

    const int t    = threadIdx.x;
    const int lane = t & 63;
    const int wave = t >> 6;
    const int wm = (wave >> 1) << 6;
    const int wn = (wave & 1) << 6;
    const int fr = lane & 15;
    const int fq = lane >> 4;
    const int rcoff = ((fq ^ ((fr >> 1) & 3)) << 3);

    const int rowc0 = (wave << 5) + (lane >> 2);          // + 16*c
    auto stage = [&](int buf, int k0) {
#pragma unroll
        for (int c = 0; c < 2; ++c) {
            int row = rowc0 + (c << 4);
            int lg  = (((lane & 3) ^ ((row >> 1) & 3)) << 3);
            int ldsoff = ((wave << 5) + (c << 4)) * 32;   // wave-uniform
            gll16(Wb + (size_t)(m0 + row) * LSEQ + k0 + lg, &Wl[buf][ldsoff]);
            gll16(Bb + (size_t)(n0 + row) * LSEQ + k0 + lg, &Bl[buf][ldsoff]);
        }
    };

    stage(0, 0);
    __syncthreads();

    f32x4 acc[4][4];
#pragma unroll
    for (int i = 0; i < 4; ++i)
#pragma unroll
        for (int j = 0; j < 4; ++j) acc[i][j] = (f32x4){0.f, 0.f, 0.f, 0.f};

    constexpr int NK = 16;   // 512/32
    for (int it = 0; it < NK; ++it) {
        int cur = it & 1;
        if (it + 1 < NK) stage(cur ^ 1, (it + 1) << 5);   // async, other buffer

        f16x8 af[4], bfr[4];
#pragma unroll
        for (int i = 0; i < 4; ++i) {
            af[i]  = *(const f16x8*)&Wl[cur][(wm + (i << 4) + fr) * 32 + rcoff];
            bfr[i] = *(const f16x8*)&Bl[cur][(wn + (i << 4) + fr) * 32 + rcoff];
        }
#pragma unroll
        for (int mi = 0; mi < 4; ++mi)
#pragma unroll
            for (int ni = 0; ni < 4; ++ni)
                acc[mi][ni] = mfma16h(af[mi], bfr[ni], acc[mi][ni]);
        __syncthreads();
    }

    const float* mmb = mask_m + (b << 9) + m0;
#pragma unroll
    for (int mi = 0; mi < 4; ++mi)
#pragma unroll
        for (int j = 0; j < 4; ++j) {
            int row = wm + (mi << 4) + (fq << 2) + j;
            float mm = mmb[row];
#pragma unroll
            for (int ni = 0; ni < 4; ++ni) {
                int d = n0 + wn + (ni << 4) + fr;
                if (d < DDIM)
                    out[((size_t)(b << 9) + m0 + row) * DDIM + d] = mm * acc[mi][ni][j];
            }
        }
}

// ---------------------------------------------------------------------------
// Fallback wsum (round-1 style) — only if ws_size too small for fast path
// ---------------------------------------------------------------------------
template <int TRANSA>
__global__ __launch_bounds__(256) void wsum(
    const float* __restrict__ attn, const float* __restrict__ Bsrc,
    const float* __restrict__ mask_k, const float* __restrict__ mask_m,
    const float* __restrict__ Mst, const float* __restrict__ Rst,
    float* __restrict__ out)
{
    const int blk = blockIdx.x;
    const int b   = blk / 20;
    const int rem = blk % 20;
    const int m0  = (rem / 5) << 7;
    const int n0  = (rem % 5) << 7;

    const float* Ab  = attn + (size_t)b * LSEQ * LSEQ;
    const float* Bb  = Bsrc + (size_t)b * LSEQ * DDIM;
    const float* mkb = mask_k + (b << 9);

    __shared__ unsigned short Wl[128 * LDP];
    __shared__ unsigned short Bl[128 * LDP];
    __shared__ float Ml[128], Rl[128], Mm[128];

    const int t    = threadIdx.x;
    const int lane = t & 63;
    const int wave = t >> 6;
    const int wm = (wave >> 1) << 6;
    const int wn = (wave & 1) << 6;
    const int fr = lane & 15;
    const int fq = lane >> 4;

    if (t < 128) {
        Ml[t] = Mst[(b << 9) + m0 + t];
        Rl[t] = Rst[(b << 9) + m0 + t];
        Mm[t] = mask_m[(b << 9) + m0 + t];
    }
    __syncthreads();

    f32x4 acc[4][4];
#pragma unroll
    for (int i = 0; i < 4; ++i)
#pragma unroll
        for (int j = 0; j < 4; ++j) acc[i][j] = (f32x4){0.f, 0.f, 0.f, 0.f};

    for (int k0 = 0; k0 < LSEQ; k0 += 32) {
        if constexpr (TRANSA == 0) {
#pragma unroll
            for (int r = 0; r < 4; ++r) {
                int idx = t + (r << 8);
                int row = idx >> 3;
                int c4  = (idx & 7) << 2;
                float4 x  = *(const float4*)(Ab + (size_t)(m0 + row) * LSEQ + k0 + c4);
                float4 km = *(const float4*)(mkb + k0 + c4);
                float Mv = Ml[row], Rv = Rl[row];
                ushort4 w;
                w.x = (km.x != 0.f) ? f2bf(__expf(x.x - Mv) * Rv) : (unsigned short)0;
                w.y = (km.y != 0.f) ? f2bf(__expf(x.y - Mv) * Rv) : (unsigned short)0;
                w.z = (km.z != 0.f) ? f2bf(__expf(x.z - Mv) * Rv) : (unsigned short)0;
                w.w = (km.w != 0.f) ? f2bf(__expf(x.w - Mv) * Rv) : (unsigned short)0;
                *(ushort4*)&Wl[row * LDP + c4] = w;
            }
        } else {
#pragma unroll
            for (int r = 0; r < 4; ++r) {
                int mh = t & 127;
                int pq = (t >> 7) + (r << 1);
                float Mv = Ml[mh], Rv = Rl[mh];
                ushort4 w;
#pragma unroll
                for (int j = 0; j < 4; ++j) {
                    int k = k0 + (pq << 2) + j;
                    float x  = Ab[(size_t)k * LSEQ + m0 + mh];
                    float km = mkb[k];
                    ((unsigned short*)&w)[j] =
                        (km != 0.f) ? f2bf(__expf(x - Mv) * Rv) : (unsigned short)0;
                }
                *(ushort4*)&Wl[mh * LDP + (pq << 2)] = w;
            }
        }
#pragma unroll
        for (int r = 0; r < 4; ++r) {
            int d  = t & 127;
            int kq = (t >> 7) + (r << 1);
            bool valid = (n0 + d) < DDIM;
            ushort4 v;
#pragma unroll
            for (int j = 0; j < 4; ++j) {
                int k = k0 + (kq << 2) + j;
                float x = valid ? Bb[(size_t)k * DDIM + n0 + d] : 0.f;
                ((unsigned short*)&v)[j] = f2bf(x);
            }
            *(ushort4*)&Bl[d * LDP + (kq << 2)] = v;
        }
        __syncthreads();

        short8 af[4], bfr[4];
#pragma unroll
        for (int i = 0; i < 4; ++i) {
            af[i]  = *(const short8*)&Wl[(wm + (i << 4) + fr) * LDP + (fq << 3)];
            bfr[i] = *(const short8*)&Bl[(wn + (i << 4) + fr) * LDP + (fq << 3)];
        }
#pragma unroll
        for (int mi = 0; mi < 4; ++mi)
#pragma unroll
            for (int ni = 0; ni < 4; ++ni)
                acc[mi][ni] = mfma16(af[mi], bfr[ni], acc[mi][ni]);
        __syncthreads();
    }

#pragma unroll
    for (int mi = 0; mi < 4; ++mi)
#pragma unroll
        for (int j = 0; j < 4; ++j) {
            int row = wm + (mi << 4) + (fq << 2) + j;
            float mm = Mm[row];
#pragma unroll
            for (int ni = 0; ni < 4; ++ni) {
                int d = n0 + wn + (ni << 4) + fr;
                if (d < DDIM)
                    out[((size_t)(b << 9) + m0 + row) * DDIM + d] = mm * acc[mi][ni][j];
            }
        }
}

// ---------------------------------------------------------------------------
extern "C" void kernel_launch(void* const* d_in, const int* in_sizes, int n_in,
                              void* d_out, int out_size, void* d_ws, size_t ws_size,
                              hipStream_t stream)
{
    const float* P  = (const float*)d_in[0];   // encoded_premise   [64,512,600]
    const float* pm = (const float*)d_in[1];   // premise_mask      [64,512]
    const float* H  = (const float*)d_in[2];   // encoded_hypothesis[64,512,600]
    const float* hm = (const float*)d_in[3];   // hypothesis_mask   [64,512]
    float* out = (float*)d_out;
    char* o  = (char*)d_out;
    char* ws = (char*)d_ws;

    const size_t E = (size_t)DEVB * LSEQ * DDIM;   // 19,660,800 out-elems per half

    // d_out scratch layout (dispatches serialize on the stream):
    //   Hhi [0 : 39,845,888) fp16 [b][512][608] — dead after attn_gemm;
    //   hT [78,643,200 : 117,964,800) fp16 | W1 [117,964,800 : 151,519,232) fp16
    //   gemm<0> writes out[0 : 78.6M) while reading hT/W1 — disjoint.
    //   gemm<1> writes out[78.6M : 157.3M) reading only ws (W2/pT) — hT/W1 dead.
    _Float16* Hhi = (_Float16*)o;
    _Float16* hT  = (_Float16*)(o + 78643200);
    _Float16* W1  = (_Float16*)(o + 117964800);

    // ws layout (fast path, 146,276,352 B — proven available R18):
    //   attn fp32 [0 : 67,108,864) | pT [.. : 106,430,464) | W2 [.. : 139,984,896)
    //   Mp/Tp/Sp (16 stripes) [139,984,896 : 146,276,352)
    const size_t fast_need = 146276352;

    if (ws_size >= fast_need) {
        float*     attn = (float*)ws;
        _Float16*  pT   = (_Float16*)(ws + 67108864);
        _Float16*  W2   = (_Float16*)(ws + 67108864 + 39321600);
        float*     Mp   = (float*)(ws + 139984896);
        float*     Tp   = Mp + (size_t)DEVB * 16 * 512;
        float*     Sp   = Tp + (size_t)DEVB * 16 * 512;

        transcvt3<<<DEVB * 80, 256, 0, stream>>>(P, H, pT, hT, Hhi);
        attn_gemm<<<DEVB * 16, 256, 0, stream>>>(P, Hhi, attn);
        stats_w1<<<DEVB * 16, 256, 0, stream>>>(attn, hm, pm, nullptr, nullptr,
                                                W1, Mp, Tp, Sp);
        w2gen3<<<DEVB * 32, 256, 0, stream>>>(attn, pm, Mp, Tp, Sp, W2);
        gemm_gll<<<DEVB * 20, 256, 0, stream>>>(W1, hT, pm, out);
        gemm_gll<<<DEVB * 20, 256, 0, stream>>>(W2, pT, hm, out + E);
    } else {
        // fallback: attn 67.11M + partials 6.29M + M1/R1/M2/R2 0.52M of ws;
        // Hhi prep still runs (lives in d_out, dead before wsum writes out)
        float* attn = (float*)ws;
        float* Mp   = (float*)(ws + 67108864);
        float* Tp   = Mp + (size_t)DEVB * 16 * 512;
        float* Sp   = Tp + (size_t)DEVB * 16 * 512;
        float* M1   = Sp + (size_t)DEVB * 16 * 512;
        float* R1   = M1 + DEVB * LSEQ;
        float* M2   = R1 + DEVB * LSEQ;
        float* R2   = M2 + DEVB * LSEQ;

        transcvt3<<<DEVB * 80, 256, 0, stream>>>(P, H, nullptr, nullptr, Hhi);
        attn_gemm<<<DEVB * 16, 256, 0, stream>>>(P, Hhi, attn);
        stats_w1<<<DEVB * 16, 256, 0, stream>>>(attn, hm, pm, M1, R1, nullptr,
                                                Mp, Tp, Sp);
        col_merge<<<DEVB * 2, 256, 0, stream>>>(Mp, Tp, Sp, M2, R2);
        wsum<0><<<DEVB * 20, 256, 0, stream>>>(attn, H, hm, pm, M1, R1, out);
        wsum<1><<<DEVB * 20, 256, 0, stream>>>(attn, P, pm, hm, M2, R2, out + E);
    }
}

// Round 21
// 300.823 us; speedup vs baseline: 1.1212x; 1.1212x over previous
//
#include <hip/hip_runtime.h>
#include <hip/hip_bf16.h>

#define DEVB 64
#define LSEQ 512
#define DDIM 600

typedef short short8 __attribute__((ext_vector_type(8)));
typedef float f32x4 __attribute__((ext_vector_type(4)));
typedef _Float16 f16x8 __attribute__((ext_vector_type(8)));
typedef _Float16 f16x4 __attribute__((ext_vector_type(4)));

constexpr int LDP = 40;   // padded stride for fallback-wsum tiles (16B-aligned rows)

__device__ __forceinline__ unsigned short f2bf(float x) {
    union { float f; unsigned u; } v; v.f = x;
    unsigned r = v.u + 0x7fffu + ((v.u >> 16) & 1u);   // RNE
    return (unsigned short)(r >> 16);
}
__device__ __forceinline__ unsigned pk16(float a, float b) {
    union { _Float16 h[2]; unsigned u; } p;
    p.h[0] = (_Float16)a; p.h[1] = (_Float16)b;
    return p.u;
}
__device__ __forceinline__ f32x4 mfma16(short8 a, short8 b, f32x4 c) {
    return __builtin_amdgcn_mfma_f32_16x16x32_bf16(a, b, c, 0, 0, 0);
}
__device__ __forceinline__ f32x4 mfma16h(f16x8 a, f16x8 b, f32x4 c) {
    return __builtin_amdgcn_mfma_f32_16x16x32_f16(a, b, c, 0, 0, 0);
}

// global -> LDS direct DMA, 16 B per lane. LDS base must be wave-uniform;
// lane L lands at ldsbase + L*16.
typedef const __attribute__((address_space(1))) unsigned int* as1_u32p;
typedef __attribute__((address_space(3))) unsigned int* as3_u32p;
__device__ __forceinline__ void gll16(const void* g, void* l) {
    __builtin_amdgcn_global_load_lds((as1_u32p)g, (as3_u32p)l, 16, 0, 0);
}

// ---------------------------------------------------------------------------
// K0: transcvt3 — XT[b][d][r] = fp16(X[b][r][d]) for X in {P, H}, one grid.
//     64r x 128d strip per block; u32-paired LDS writes. (proven R12/R16)
//     NOTE (R17): do NOT fuse with attn_gemm (LDS union kills occupancy).
//     NOTE (R19/20): do NOT add an Hhi row-major output + DMA-B attn_gemm —
//     depth-1 gll B-staging regressed attn 89->123 µs.
// ---------------------------------------------------------------------------
__global__ __launch_bounds__(256) void transcvt3(
    const float* __restrict__ P, const float* __restrict__ H,
    _Float16* __restrict__ pT, _Float16* __restrict__ hT)
{
    int blk = blockIdx.x;
    const float* X; _Float16* XT;
    const int half = DEVB * 40;
    if (blk < half) { X = P; XT = pT; }
    else { blk -= half; X = H; XT = hT; }

    int b   = blk / 40;
    int rem = blk % 40;
    int r0  = (rem / 5) << 6;       // 8 r-tiles of 64
    int d0  = (rem % 5) << 7;       // 5 d-strips of 128
    const float* Xb = X + (size_t)b * LSEQ * DDIM;

    __shared__ unsigned T32[2][64 * 33];
    const int t  = threadIdx.x;
    const int rp = t >> 3;          // 0..31 row-pair
    const int dc = (t & 7) << 3;    // 0..56

#pragma unroll
    for (int ht_ = 0; ht_ < 2; ++ht_) {
        int dd = d0 + (ht_ << 6) + dc;
        if (dd < DDIM) {            // 8-chunks fully valid or invalid (600%8==0)
            const float* s0 = Xb + (size_t)(r0 + 2 * rp) * DDIM + dd;
            const float* s1 = s0 + DDIM;
            float4 a0 = *(const float4*)s0, a1 = *(const float4*)(s0 + 4);
            float4 b0 = *(const float4*)s1, b1 = *(const float4*)(s1 + 4);
            float xa[8] = {a0.x, a0.y, a0.z, a0.w, a1.x, a1.y, a1.z, a1.w};
            float xb[8] = {b0.x, b0.y, b0.z, b0.w, b1.x, b1.y, b1.z, b1.w};
#pragma unroll
            for (int j = 0; j < 8; ++j)
                T32[ht_][(dc + j) * 33 + rp] = pk16(xa[j], xb[j]);
        }
    }
    __syncthreads();

    const int dl = t >> 2;          // 0..63
    const int q  = t & 3;
#pragma unroll
    for (int ht_ = 0; ht_ < 2; ++ht_) {
        int d = d0 + (ht_ << 6) + dl;
        if (d < DDIM) {
            unsigned buf[8];
#pragma unroll
            for (int i = 0; i < 8; ++i)
                buf[i] = T32[ht_][dl * 33 + q * 8 + i];
            unsigned* dst = (unsigned*)(XT + ((size_t)b * DDIM + d) * LSEQ + r0) + q * 8;
            *(uint4*)(dst)     = *(uint4*)&buf[0];
            *(uint4*)(dst + 4) = *(uint4*)&buf[4];
        }
    }
}

// ---------------------------------------------------------------------------
// K1: attn[b][p][h] = sum_d P[b][p][d] * H[b][h][d]   (fp32 out)
// R9/R12 proven: 256 threads, 128x128, fp32 direct reads, hi/lo fp16 split in
// LDS-write phase, 48 KB dbuf, chunk-XOR swizzle (0 conflicts). No 2nd
// launch_bounds arg (R10: VGPR capped at 64 -> accumulator spill).
// ---------------------------------------------------------------------------
__global__ __launch_bounds__(256) void attn_gemm(
    const float* __restrict__ P, const float* __restrict__ H,
    float* __restrict__ attn)
{
    const int bid = blockIdx.x;
    const int swz = (bid & 7) * 128 + (bid >> 3);   // 1024 blocks, 8 XCDs
    const int b  = swz >> 4;
    const int pt = ((swz >> 2) & 3) << 7;
    const int ht = (swz & 3) << 7;
    const float* Pb = P + ((size_t)b * LSEQ + pt) * DDIM;
    const float* Hb = H + ((size_t)b * LSEQ + ht) * DDIM;
    float* Ab = attn + (size_t)b * LSEQ * LSEQ;

    __shared__ _Float16 Ah[2][128 * 32], Al[2][128 * 32], Bh[2][128 * 32];

    const int t    = threadIdx.x;
    const int lane = t & 63;
    const int wave = t >> 6;
    const int wm = (wave >> 1) << 6;
    const int wn = (wave & 1) << 6;
    const int fr = lane & 15;
    const int fq = lane >> 4;
    const int srow = t >> 2;          // 0..63 (r=1 adds 64)
    const int sc8  = (t & 3) << 3;    // logical col chunk base (8 elems)

    const int wchunk = (t & 3) ^ ((srow >> 1) & 3);
    const int woff   = srow * 32 + (wchunk << 3);          // + r*64*32
    const int rcoff  = ((fq ^ ((fr >> 1) & 3)) << 3);

    float4 pf[8];
    const float4 fz = {0.f, 0.f, 0.f, 0.f};
    auto issue = [&](int k0) {
        bool ok = (k0 + sc8) < DDIM;   // zero the 600..607 tail chunk
#pragma unroll
        for (int r = 0; r < 2; ++r) {
            size_t base = (size_t)(srow + (r << 6)) * DDIM + k0 + sc8;
            if (ok) {
                pf[r * 4 + 0] = *(const float4*)(Pb + base);
                pf[r * 4 + 1] = *(const float4*)(Pb + base + 4);
                pf[r * 4 + 2] = *(const float4*)(Hb + base);
                pf[r * 4 + 3] = *(const float4*)(Hb + base + 4);
            } else {
                pf[r * 4 + 0] = fz; pf[r * 4 + 1] = fz;
                pf[r * 4 + 2] = fz; pf[r * 4 + 3] = fz;
            }
        }
    };
    auto wr = [&](int buf) {
#pragma unroll
        for (int r = 0; r < 2; ++r) {
            float4 a0 = pf[r * 4 + 0], a1 = pf[r * 4 + 1];
            float4 h0 = pf[r * 4 + 2], h1 = pf[r * 4 + 3];
            float af[8] = {a0.x, a0.y, a0.z, a0.w, a1.x, a1.y, a1.z, a1.w};
            float hf[8] = {h0.x, h0.y, h0.z, h0.w, h1.x, h1.y, h1.z, h1.w};
            f16x8 hi, lo, bh;
#pragma unroll
            for (int j = 0; j < 8; ++j) {
                hi[j] = (_Float16)af[j];
                lo[j] = (_Float16)(af[j] - (float)hi[j]);
                bh[j] = (_Float16)hf[j];
            }
            int off = woff + (r << 11);                    // r*64*32
            *(f16x8*)&Ah[buf][off] = hi;
            *(f16x8*)&Al[buf][off] = lo;
            *(f16x8*)&Bh[buf][off] = bh;
        }
    };

    issue(0);
    wr(0);
    issue(32);
    __syncthreads();

    f32x4 acc[4][4];
#pragma unroll
    for (int i = 0; i < 4; ++i)
#pragma unroll
        for (int j = 0; j < 4; ++j) acc[i][j] = (f32x4){0.f, 0.f, 0.f, 0.f};

    constexpr int NK = 19;   // ceil(600/32)
    int cur = 0;
    for (int it = 0; it < NK; ++it) {
        f16x8 ah[4], al[4], bh[4];
#pragma unroll
        for (int i = 0; i < 4; ++i) {
            int ra = (wm + (i << 4) + fr) * 32 + rcoff;
            int rb = (wn + (i << 4) + fr) * 32 + rcoff;
            ah[i] = *(const f16x8*)&Ah[cur][ra];
            al[i] = *(const f16x8*)&Al[cur][ra];
            bh[i] = *(const f16x8*)&Bh[cur][rb];
        }
        if (it + 1 < NK) {
            wr(cur ^ 1);                       // cvt + stage tile it+1
            if (it + 2 < NK) issue((it + 2) << 5);
        }
#pragma unroll
        for (int mi = 0; mi < 4; ++mi)
#pragma unroll
            for (int ni = 0; ni < 4; ++ni) {
                f32x4 c = acc[mi][ni];
                c = mfma16h(ah[mi], bh[ni], c);
                c = mfma16h(al[mi], bh[ni], c);
                acc[mi][ni] = c;
            }
        __syncthreads();
        cur ^= 1;
    }

#pragma unroll
    for (int mi = 0; mi < 4; ++mi)
#pragma unroll
        for (int ni = 0; ni < 4; ++ni)
#pragma unroll
            for (int j = 0; j < 4; ++j) {
                int p = pt + wm + (mi << 4) + (fq << 2) + j;
                int h = ht + wn + (ni << 4) + fr;
                Ab[(size_t)p * LSEQ + h] = acc[mi][ni][j];
            }
}

// ---------------------------------------------------------------------------
// K2: stats_w1 — ONE pass over attn per 32-row stripe (16 stripes/batch,
// grid DEVB*16 = 1024 blocks -> 4 blocks/CU; proven R18):
//   per-row (over h): W1 fp16 (hm-masked softmax); M1/R1 written only in
//   fallback mode (W1 == nullptr)
//   per-col partials (over p, pm-masked online): Mp/Tp/Sp [b][16][512]
// ---------------------------------------------------------------------------
__global__ __launch_bounds__(256) void stats_w1(
    const float* __restrict__ attn, const float* __restrict__ hmask,
    const float* __restrict__ pmask,
    float* __restrict__ M1, float* __restrict__ R1,
    _Float16* __restrict__ W1,
    float* __restrict__ Mp, float* __restrict__ Tp, float* __restrict__ Sp)
{
    int b      = blockIdx.x >> 4;
    int stripe = blockIdx.x & 15;
    int lane   = threadIdx.x & 63;
    int wave   = threadIdx.x >> 6;
    const float* hm = hmask + (b << 9);
    const float* pm = pmask + (b << 9);

    float4 m0 = *(const float4*)(hm + (lane << 3));
    float4 m1 = *(const float4*)(hm + (lane << 3) + 4);
    float mk[8] = {m0.x, m0.y, m0.z, m0.w, m1.x, m1.y, m1.z, m1.w};

    float cM[8], cT[8], cS[8];
#pragma unroll
    for (int j = 0; j < 8; ++j) { cM[j] = -1e30f; cT[j] = 0.f; cS[j] = 0.f; }

    for (int i = 0; i < 8; ++i) {
        int row   = (stripe << 5) + (wave << 3) + i;
        int rowid = (b << 9) + row;
        const float* rp = attn + (size_t)rowid * LSEQ + (lane << 3);
        float4 s0 = *(const float4*)rp;
        float4 s1 = *(const float4*)(rp + 4);
        float s[8] = {s0.x, s0.y, s0.z, s0.w, s1.x, s1.y, s1.z, s1.w};

        float v[8];
#pragma unroll
        for (int j = 0; j < 8; ++j) v[j] = s[j] * mk[j];
        float mx = -1e30f;
#pragma unroll
        for (int j = 0; j < 8; ++j) mx = fmaxf(mx, v[j]);
#pragma unroll
        for (int off = 32; off; off >>= 1) mx = fmaxf(mx, __shfl_xor(mx, off));

        float e[8], T = 0.f, S = 0.f;
#pragma unroll
        for (int j = 0; j < 8; ++j) { e[j] = __expf(v[j] - mx); T += mk[j] * e[j]; S += e[j]; }
#pragma unroll
        for (int off = 32; off; off >>= 1) { T += __shfl_xor(T, off); S += __shfl_xor(S, off); }
        float R = 1.f / (T + 1e-13f * S);

        if (W1) {
            union { f16x8 v8; _Float16 h[8]; } wv;
#pragma unroll
            for (int j = 0; j < 8; ++j) wv.h[j] = (_Float16)(mk[j] * e[j] * R);
            *(f16x8*)(W1 + (size_t)rowid * LSEQ + (lane << 3)) = wv.v8;
        } else if (lane == 0) {
            M1[rowid] = mx; R1[rowid] = R;
        }

        float pmv = pm[row];
#pragma unroll
        for (int j = 0; j < 8; ++j) {
            float v2 = s[j] * pmv;
            float nm = fmaxf(cM[j], v2);
            float sc = __expf(cM[j] - nm);
            float e2 = __expf(v2 - nm);
            cT[j] = cT[j] * sc + pmv * e2;
            cS[j] = cS[j] * sc + e2;
            cM[j] = nm;
        }
    }

    __shared__ float LM[4][512], LT[4][512], LS[4][512];
#pragma unroll
    for (int j = 0; j < 8; ++j) {
        int c = (lane << 3) + j;
        LM[wave][c] = cM[j]; LT[wave][c] = cT[j]; LS[wave][c] = cS[j];
    }
    __syncthreads();

    size_t base = (size_t)((b << 4) + stripe) * 512;
    for (int cc = threadIdx.x; cc < 512; cc += 256) {
        float gm = fmaxf(fmaxf(LM[0][cc], LM[1][cc]), fmaxf(LM[2][cc], LM[3][cc]));
        float gT = 0.f, gS = 0.f;
#pragma unroll
        for (int w = 0; w < 4; ++w) {
            float sc = __expf(LM[w][cc] - gm);
            gT += LT[w][cc] * sc;
            gS += LS[w][cc] * sc;
        }
        Mp[base + cc] = gm; Tp[base + cc] = gT; Sp[base + cc] = gS;
    }
}

// ---------------------------------------------------------------------------
// K3 (fallback only): col_merge — merge 16 stripe partials -> M2, R2
// ---------------------------------------------------------------------------
__global__ __launch_bounds__(256) void col_merge(
    const float* __restrict__ Mp, const float* __restrict__ Tp,
    const float* __restrict__ Sp, float* __restrict__ M2, float* __restrict__ R2)
{
    int b = blockIdx.x >> 1;
    int c = ((blockIdx.x & 1) << 8) + threadIdx.x;
    float gm = -1e30f, gT = 0.f, gS = 0.f;
#pragma unroll
    for (int st = 0; st < 16; ++st) {
        size_t idx = (size_t)((b << 4) + st) * 512 + c;
        float m = Mp[idx], tt = Tp[idx], ss = Sp[idx];
        float nm  = fmaxf(gm, m);
        float sc1 = __expf(gm - nm), sc2 = __expf(m - nm);
        gT = gT * sc1 + tt * sc2;
        gS = gS * sc1 + ss * sc2;
        gm = nm;
    }
    M2[(b << 9) + c] = gm;
    R2[(b << 9) + c] = 1.f / (gT + 1e-13f * gS);
}

// ---------------------------------------------------------------------------
// K4: w2gen3 — per-block 16-stripe merge then W2[b][h][p] fp16 via u32-paired
//     LDS transpose (proven R12). Tile = 64p x 128h.
// ---------------------------------------------------------------------------
__global__ __launch_bounds__(256) void w2gen3(
    const float* __restrict__ attn, const float* __restrict__ pmask,
    const float* __restrict__ Mp, const float* __restrict__ Tp,
    const float* __restrict__ Sp, _Float16* __restrict__ W2)
{
    int blk = blockIdx.x;
    int b  = blk >> 5;
    int p0 = ((blk >> 2) & 7) << 6;
    int h0 = (blk & 3) << 7;
    const float* Ab = attn + (size_t)b * LSEQ * LSEQ;
    const float* pm = pmask + (b << 9);

    __shared__ float sM[128], sR[128];
    __shared__ unsigned T32[128 * 33];
    const int t = threadIdx.x;
    if (t < 128) {
        float gm = -1e30f, gT = 0.f, gS = 0.f;
#pragma unroll
        for (int st = 0; st < 16; ++st) {
            size_t idx = (size_t)((b << 4) + st) * 512 + h0 + t;
            float m = Mp[idx], tt = Tp[idx], ss = Sp[idx];
            float nm  = fmaxf(gm, m);
            float sc1 = __expf(gm - nm), sc2 = __expf(m - nm);
            gT = gT * sc1 + tt * sc2;
            gS = gS * sc1 + ss * sc2;
            gm = nm;
        }
        sM[t] = gm;
        sR[t] = 1.f / (gT + 1e-13f * gS);
    }
    __syncthreads();

#pragma unroll
    for (int it = 0; it < 4; ++it) {
        int g  = t + (it << 8);
        int pp = g >> 5;           // 0..31 p-pair
        int hc = (g & 31) << 2;    // 0..124
        const float* s0 = Ab + (size_t)(p0 + 2 * pp) * LSEQ + h0 + hc;
        float4 xa = *(const float4*)s0;
        float4 xb = *(const float4*)(s0 + LSEQ);
        float pa = pm[p0 + 2 * pp];
        float pb = pm[p0 + 2 * pp + 1];
        float a[4] = {xa.x, xa.y, xa.z, xa.w};
        float bb[4] = {xb.x, xb.y, xb.z, xb.w};
#pragma unroll
        for (int j = 0; j < 4; ++j) {
            float wa = (pa != 0.f) ? __expf(a[j]  - sM[hc + j]) * sR[hc + j] : 0.f;
            float wb = (pb != 0.f) ? __expf(bb[j] - sM[hc + j]) * sR[hc + j] : 0.f;
            T32[(hc + j) * 33 + pp] = pk16(wa, wb);
        }
    }
    __syncthreads();

    const int hl = t >> 1;          // 0..127
    const int q  = t & 1;
    unsigned buf[16];
#pragma unroll
    for (int i = 0; i < 16; ++i)
        buf[i] = T32[hl * 33 + q * 16 + i];
    unsigned* dst = (unsigned*)(W2 + ((size_t)(b << 9) + h0 + hl) * LSEQ + p0) + q * 16;
#pragma unroll
    for (int i = 0; i < 4; ++i)
        *(uint4*)(dst + 4 * i) = *(uint4*)&buf[4 * i];
}

// ---------------------------------------------------------------------------
// K5: gemm_gll — out[b][m][d] = mask_m[m] * sum_k W[b][m][k] * BT[b][d][k]
//     m97-style: BK=32, dbuf, both operands via global_load_lds width=16,
//     pre-swizzled source (chunk XOR (row>>1)&3). 32 KB LDS. (proven R16)
// ---------------------------------------------------------------------------
__global__ __launch_bounds__(256) void gemm_gll(
    const _Float16* __restrict__ W, const _Float16* __restrict__ BT,
    const float* __restrict__ mask_m, float* __restrict__ out)
{
    const int bid = blockIdx.x;
    const int swz = (bid & 7) * 160 + (bid >> 3);   // 1280 blocks, 8 XCDs
    const int b   = swz / 20;
    const int rem = swz % 20;
    const int m0  = (rem / 5) << 7;
    const int n0  = (rem % 5) << 7;
    const _Float16* Wb = W  + (size_t)b * LSEQ * LSEQ;
    const _Float16* Bb = BT + (size_t)b * DDIM * LSEQ;

    __shared__ _Float16 Wl[2][128 * 32];
    __shared__ _Float16 Bl[2][128 * 32];

    const int t    = threadIdx.x;
    const int lane = t & 63;
    const int wave = t >> 6;
    const int wm = (wave >> 1) << 6;
    const int wn = (wave & 1) << 6;
    const int fr = lane & 15;
    const int fq = lane >> 4;
    const int rcoff = ((fq ^ ((fr >> 1) & 3)) << 3);

    const int rowc0 = (wave << 5) + (lane >> 2);          // + 16*c
    auto stage = [&](int buf, int k0) {
#pragma unroll
        for (int c = 0; c < 2; ++c) {
            int row = rowc0 + (c << 4);
            int lg  = (((lane & 3) ^ ((row >> 1) & 3)) << 3);
            int ldsoff = ((wave << 5) + (c << 4)) * 32;   // wave-uniform
            gll16(Wb + (size_t)(m0 + row) * LSEQ + k0 + lg, &Wl[buf][ldsoff]);
            gll16(Bb + (size_t)(n0 + row) * LSEQ + k0 + lg, &Bl[buf][ldsoff]);
        }
    };

    stage(0, 0);
    __syncthreads();

    f32x4 acc[4][4];
#pragma unroll
    for (int i = 0; i < 4; ++i)
#pragma unroll
        for (int j = 0; j < 4; ++j) acc[i][j] = (f32x4){0.f, 0.f, 0.f, 0.f};

    constexpr int NK = 16;   // 512/32
    for (int it = 0; it < NK; ++it) {
        int cur = it & 1;
        if (it + 1 < NK) stage(cur ^ 1, (it + 1) << 5);   // async, other buffer

        f16x8 af[4], bfr[4];
#pragma unroll
        for (int i = 0; i < 4; ++i) {
            af[i]  = *(const f16x8*)&Wl[cur][(wm + (i << 4) + fr) * 32 + rcoff];
            bfr[i] = *(const f16x8*)&Bl[cur][(wn + (i << 4) + fr) * 32 + rcoff];
        }
#pragma unroll
        for (int mi = 0; mi < 4; ++mi)
#pragma unroll
            for (int ni = 0; ni < 4; ++ni)
                acc[mi][ni] = mfma16h(af[mi], bfr[ni], acc[mi][ni]);
        __syncthreads();
    }

    const float* mmb = mask_m + (b << 9) + m0;
#pragma unroll
    for (int mi = 0; mi < 4; ++mi)
#pragma unroll
        for (int j = 0; j < 4; ++j) {
            int row = wm + (mi << 4) + (fq << 2) + j;
            float mm = mmb[row];
#pragma unroll
            for (int ni = 0; ni < 4; ++ni) {
                int d = n0 + wn + (ni << 4) + fr;
                if (d < DDIM)
                    out[((size_t)(b << 9) + m0 + row) * DDIM + d] = mm * acc[mi][ni][j];
            }
        }
}

// ---------------------------------------------------------------------------
// Fallback wsum (round-1 style) — only if ws_size too small for fast path
// ---------------------------------------------------------------------------
template <int TRANSA>
__global__ __launch_bounds__(256) void wsum(
    const float* __restrict__ attn, const float* __restrict__ Bsrc,
    const float* __restrict__ mask_k, const float* __restrict__ mask_m,
    const float* __restrict__ Mst, const float* __restrict__ Rst,
    float* __restrict__ out)
{
    const int blk = blockIdx.x;
    const int b   = blk / 20;
    const int rem = blk % 20;
    const int m0  = (rem / 5) << 7;
    const int n0  = (rem % 5) << 7;

    const float* Ab  = attn + (size_t)b * LSEQ * LSEQ;
    const float* Bb  = Bsrc + (size_t)b * LSEQ * DDIM;
    const float* mkb = mask_k + (b << 9);

    __shared__ unsigned short Wl[128 * LDP];
    __shared__ unsigned short Bl[128 * LDP];
    __shared__ float Ml[128], Rl[128], Mm[128];

    const int t    = threadIdx.x;
    const int lane = t & 63;
    const int wave = t >> 6;
    const int wm = (wave >> 1) << 6;
    const int wn = (wave & 1) << 6;
    const int fr = lane & 15;
    const int fq = lane >> 4;

    if (t < 128) {
        Ml[t] = Mst[(b << 9) + m0 + t];
        Rl[t] = Rst[(b << 9) + m0 + t];
        Mm[t] = mask_m[(b << 9) + m0 + t];
    }
    __syncthreads();

    f32x4 acc[4][4];
#pragma unroll
    for (int i = 0; i < 4; ++i)
#pragma unroll
        for (int j = 0; j < 4; ++j) acc[i][j] = (f32x4){0.f, 0.f, 0.f, 0.f};

    for (int k0 = 0; k0 < LSEQ; k0 += 32) {
        if constexpr (TRANSA == 0) {
#pragma unroll
            for (int r = 0; r < 4; ++r) {
                int idx = t + (r << 8);
                int row = idx >> 3;
                int c4  = (idx & 7) << 2;
                float4 x  = *(const float4*)(Ab + (size_t)(m0 + row) * LSEQ + k0 + c4);
                float4 km = *(const float4*)(mkb + k0 + c4);
                float Mv = Ml[row], Rv = Rl[row];
                ushort4 w;
                w.x = (km.x != 0.f) ? f2bf(__expf(x.x - Mv) * Rv) : (unsigned short)0;
                w.y = (km.y != 0.f) ? f2bf(__expf(x.y - Mv) * Rv) : (unsigned short)0;
                w.z = (km.z != 0.f) ? f2bf(__expf(x.z - Mv) * Rv) : (unsigned short)0;
                w.w = (km.w != 0.f) ? f2bf(__expf(x.w - Mv) * Rv) : (unsigned short)0;
                *(ushort4*)&Wl[row * LDP + c4] = w;
            }
        } else {
#pragma unroll
            for (int r = 0; r < 4; ++r) {
                int mh = t & 127;
                int pq = (t >> 7) + (r << 1);
                float Mv = Ml[mh], Rv = Rl[mh];
                ushort4 w;
#pragma unroll
                for (int j = 0; j < 4; ++j) {
                    int k = k0 + (pq << 2) + j;
                    float x  = Ab[(size_t)k * LSEQ + m0 + mh];
                    float km = mkb[k];
                    ((unsigned short*)&w)[j] =
                        (km != 0.f) ? f2bf(__expf(x - Mv) * Rv) : (unsigned short)0;
                }
                *(ushort4*)&Wl[mh * LDP + (pq << 2)] = w;
            }
        }
#pragma unroll
        for (int r = 0; r < 4; ++r) {
            int d  = t & 127;
            int kq = (t >> 7) + (r << 1);
            bool valid = (n0 + d) < DDIM;
            ushort4 v;
#pragma unroll
            for (int j = 0; j < 4; ++j) {
                int k = k0 + (kq << 2) + j;
                float x = valid ? Bb[(size_t)k * DDIM + n0 + d] : 0.f;
                ((unsigned short*)&v)[j] = f2bf(x);
            }
            *(ushort4*)&Bl[d * LDP + (kq << 2)] = v;
        }
        __syncthreads();

        short8 af[4], bfr[4];
#pragma unroll
        for (int i = 0; i < 4; ++i) {
            af[i]  = *(const short8*)&Wl[(wm + (i << 4) + fr) * LDP + (fq << 3)];
            bfr[i] = *(const short8*)&Bl[(wn + (i << 4) + fr) * LDP + (fq << 3)];
        }
#pragma unroll
        for (int mi = 0; mi < 4; ++mi)
#pragma unroll
            for (int ni = 0; ni < 4; ++ni)
                acc[mi][ni] = mfma16(af[mi], bfr[ni], acc[mi][ni]);
        __syncthreads();
    }

#pragma unroll
    for (int mi = 0; mi < 4; ++mi)
#pragma unroll
        for (int j = 0; j < 4; ++j) {
            int row = wm + (mi << 4) + (fq << 2) + j;
            float mm = Mm[row];
#pragma unroll
            for (int ni = 0; ni < 4; ++ni) {
                int d = n0 + wn + (ni << 4) + fr;
                if (d < DDIM)
                    out[((size_t)(b << 9) + m0 + row) * DDIM + d] = mm * acc[mi][ni][j];
            }
        }
}

// ---------------------------------------------------------------------------
extern "C" void kernel_launch(void* const* d_in, const int* in_sizes, int n_in,
                              void* d_out, int out_size, void* d_ws, size_t ws_size,
                              hipStream_t stream)
{
    const float* P  = (const float*)d_in[0];   // encoded_premise   [64,512,600]
    const float* pm = (const float*)d_in[1];   // premise_mask      [64,512]
    const float* H  = (const float*)d_in[2];   // encoded_hypothesis[64,512,600]
    const float* hm = (const float*)d_in[3];   // hypothesis_mask   [64,512]
    float* out = (float*)d_out;
    char* o  = (char*)d_out;
    char* ws = (char*)d_ws;

    const size_t E = (size_t)DEVB * LSEQ * DDIM;   // 19,660,800 out-elems per half

    // d_out scratch layout (proven R12; dispatches serialize on the stream):
    //   hT [78,643,200 : 117,964,800) fp16 | W1 [117,964,800 : 151,519,232) fp16
    //   gemm<0> writes out[0 : 78.6M) while reading hT/W1 — disjoint.
    //   gemm<1> writes out[78.6M : 157.3M) reading only ws (W2/pT) — hT/W1 dead.
    _Float16* hT = (_Float16*)(o + 78643200);
    _Float16* W1 = (_Float16*)(o + 117964800);

    // ws layout (fast path, 146,276,352 B — proven available R18):
    //   attn fp32 [0 : 67,108,864) | pT [.. : 106,430,464) | W2 [.. : 139,984,896)
    //   Mp/Tp/Sp (16 stripes) [139,984,896 : 146,276,352)
    const size_t fast_need = 146276352;

    if (ws_size >= fast_need) {
        float*     attn = (float*)ws;
        _Float16*  pT   = (_Float16*)(ws + 67108864);
        _Float16*  W2   = (_Float16*)(ws + 67108864 + 39321600);
        float*     Mp   = (float*)(ws + 139984896);
        float*     Tp   = Mp + (size_t)DEVB * 16 * 512;
        float*     Sp   = Tp + (size_t)DEVB * 16 * 512;

        transcvt3<<<DEVB * 80, 256, 0, stream>>>(P, H, pT, hT);
        attn_gemm<<<DEVB * 16, 256, 0, stream>>>(P, H, attn);
        stats_w1<<<DEVB * 16, 256, 0, stream>>>(attn, hm, pm, nullptr, nullptr,
                                                W1, Mp, Tp, Sp);
        w2gen3<<<DEVB * 32, 256, 0, stream>>>(attn, pm, Mp, Tp, Sp, W2);
        gemm_gll<<<DEVB * 20, 256, 0, stream>>>(W1, hT, pm, out);
        gemm_gll<<<DEVB * 20, 256, 0, stream>>>(W2, pT, hm, out + E);
    } else {
        // fallback: attn 67.11M + partials 6.29M + M1/R1/M2/R2 0.52M of ws
        float* attn = (float*)ws;
        float* Mp   = (float*)(ws + 67108864);
        float* Tp   = Mp + (size_t)DEVB * 16 * 512;
        float* Sp   = Tp + (size_t)DEVB * 16 * 512;
        float* M1   = Sp + (size_t)DEVB * 16 * 512;
        float* R1   = M1 + DEVB * LSEQ;
        float* M2   = R1 + DEVB * LSEQ;
        float* R2   = M2 + DEVB * LSEQ;

        attn_gemm<<<DEVB * 16, 256, 0, stream>>>(P, H, attn);
        stats_w1<<<DEVB * 16, 256, 0, stream>>>(attn, hm, pm, M1, R1, nullptr,
                                                Mp, Tp, Sp);
        col_merge<<<DEVB * 2, 256, 0, stream>>>(Mp, Tp, Sp, M2, R2);
        wsum<0><<<DEVB * 20, 256, 0, stream>>>(attn, H, hm, pm, M1, R1, out);
        wsum<1><<<DEVB * 20, 256, 0, stream>>>(attn, P, pm, hm, M2, R2, out + E);
    }
}